// Round 17
// baseline (95.156 us; speedup 1.0000x reference)
//
#include <hip/hip_runtime.h>

typedef _Float16 f16x2 __attribute__((ext_vector_type(2)));
typedef _Float16 f16x8 __attribute__((ext_vector_type(8)));
typedef __fp16   fp16v2 __attribute__((ext_vector_type(2)));
typedef float    f32x16 __attribute__((ext_vector_type(16)));
typedef unsigned int u32x4 __attribute__((ext_vector_type(4)));

#define TROWSTR 25
#define REP 2        // diagnostic: push each variant's dispatch above the 39us fills

__device__ __forceinline__ f16x2 pk2(float lo, float hi) {
    fp16v2 p = __builtin_amdgcn_cvt_pkrtz(lo, hi);
    return __builtin_bit_cast(f16x2, p);
}
__device__ __forceinline__ unsigned int pkbits(f16x2 a, f16x2 b) {
    f16x2 r = a * b;
    return __builtin_bit_cast(unsigned int, r);
}

// ---- prep: C (f32) -> flattened-K f16 B table (validated R10) ----
__global__ __launch_bounds__(256) void prep_B(const float* __restrict__ coeffs,
                                              f16x8* __restrict__ wsB)
{
    int chunk = blockIdx.x * 256 + threadIdx.x;
    int s = chunk >> 6, l = chunk & 63;
    int i = l & 31, h = l >> 5;
    f16x8 v;
    if (i < 24) {
        const float* src = coeffs + i * 576 + 16 * s + 8 * h;
#pragma unroll
        for (int e = 0; e < 8; ++e) v[e] = (_Float16)src[e];
    } else {
#pragma unroll
        for (int e = 0; e < 8; ++e) v[e] = (_Float16)0.f;
    }
    wsB[chunk] = v;
}

// ---- probe: V=0 full (correct out) | V=1 MFMA-only floor | V=2 VALU-only floor ----
// Structure identical to R16 (2048 waves, 8 iters x 32x32 M-tile, pinned B).
template<int V>
__global__ __launch_bounds__(256, 2) void fourier_probe(
    const float* __restrict__ xyz,
    const f16x8* __restrict__ wsB,
    float* __restrict__ out,
    float* __restrict__ tok)
{
    __shared__ __align__(16) float Tl[4 * 32 * TROWSTR];

    const int tid  = threadIdx.x;
    const int wave = tid >> 6;
    const int lane = tid & 63;
    const int h    = lane >> 5;
    const int mr   = lane & 31;
    const bool hb  = (h != 0);

    const int pw = (blockIdx.x * 4 + wave) * 256;

    u32x4 btw[36];
#pragma unroll
    for (int s = 1; s < 36; ++s) btw[s] = ((const u32x4*)wsB)[s * 64 + lane];
#pragma unroll
    for (int s = 1; s < 36; ++s) asm volatile("" : "+v"(btw[s]));

    float* Tw = Tl + wave * (32 * TROWSTR);
    float tokacc = 0.f;

#pragma unroll 1
    for (int rep = 0; rep < REP; ++rep) {
        float cx = xyz[3 * (pw + mr) + 0];
        float cy = xyz[3 * (pw + mr) + 1];
        float cz = xyz[3 * (pw + mr) + 2];
        asm volatile("" : "+v"(cx), "+v"(cy), "+v"(cz));   // defeat cross-rep CSE

#pragma unroll 1
        for (int it = 0; it < 8; ++it) {
            const int pp0 = pw + it * 32;
            int pn = (it < 7) ? (pp0 + 32 + mr) : (pw + mr);
            float nx = xyz[3 * pn + 0];
            float ny = xyz[3 * pn + 1];
            float nz = xyz[3 * pn + 2];

            float syv[24];
            f16x2 szR[3][4];
            if (V != 1) {   // trig setup (skipped in MFMA-only)
                float s1y = __builtin_amdgcn_sinf(cy);
                float c1y = __builtin_amdgcn_cosf(cy);
                float c2y = 2.f * c1y;
                syv[0] = 0.f; syv[1] = s1y;
#pragma unroll
                for (int j = 2; j < 24; ++j) syv[j] = fmaf(c2y, syv[j - 1], -syv[j - 2]);
                float s1 = __builtin_amdgcn_sinf(cz);
                float c1 = __builtin_amdgcn_cosf(cz);
                float w8 = __builtin_amdgcn_fractf(8.f * cz);
                float s8 = __builtin_amdgcn_sinf(w8);
                float c8 = __builtin_amdgcn_cosf(w8);
                float s16 = 2.f * s8 * c8;
                float c16 = fmaf(2.f * c8, c8, -1.f);
                float c2z = 2.f * c1;
#pragma unroll
                for (int t = 0; t < 3; ++t) {
                    float sk, ck;
                    if (t == 0) { sk = hb ? s8  : 0.f;  ck = hb ? c8  : 1.f;  }
                    if (t == 1) { sk = hb ? s16 : s8;   ck = hb ? c16 : c8;   }
                    if (t == 2) { sk = hb ? 0.f : s16;  ck = hb ? 1.f : c16;  }
                    float v[8];
                    v[0] = sk;
                    v[1] = fmaf(sk, c1, ck * s1);
#pragma unroll
                    for (int e = 2; e < 8; ++e) v[e] = fmaf(c2z, v[e - 1], -v[e - 2]);
#pragma unroll
                    for (int q = 0; q < 4; ++q) szR[t][q] = pk2(v[2 * q], v[2 * q + 1]);
                }
            }

            f32x16 acc = {};

#pragma unroll
            for (int s = 1; s < 36; ++s) {
                const int t  = (2 * s) % 3;
                const int j0 = (2 * s) / 3;
                const int j1 = (2 * s + 1) / 3;
                u32x4 aw;
                if (V != 1) {
                    float hy = (j0 == j1) ? syv[j0] : (hb ? syv[j1] : syv[j0]);
                    f16x2 hy2 = pk2(hy, hy);
                    aw[0] = pkbits(hy2, szR[t][0]);
                    aw[1] = pkbits(hy2, szR[t][1]);
                    aw[2] = pkbits(hy2, szR[t][2]);
                    aw[3] = pkbits(hy2, szR[t][3]);
                } else {
                    aw = btw[(s % 35) + 1] ;   // constant-ish A, no VALU build
                }
                if (V != 2) {
                    f16x8 a = __builtin_bit_cast(f16x8, aw);
                    f16x8 b = __builtin_bit_cast(f16x8, btw[s]);
                    acc = __builtin_amdgcn_mfma_f32_32x32x16_f16(a, b, acc, 0, 0, 0);
                } else {
                    // keep A-build live without MFMA (rule #17)
                    asm volatile("" :: "v"(aw[0]), "v"(aw[1]), "v"(aw[2]), "v"(aw[3]));
                }
            }

            if (V == 0) {
                if (mr < 24) {
#pragma unroll
                    for (int r = 0; r < 16; ++r) {
                        int row = (r & 3) + 8 * (r >> 2) + 4 * h;
                        Tw[row * TROWSTR + mr] = acc[r];
                    }
                }
                asm volatile("s_waitcnt lgkmcnt(0)" ::: "memory");
                float sx1 = __builtin_amdgcn_sinf(cx);
                float cx1 = __builtin_amdgcn_cosf(cx);
                const float c2x = 2.f * cx1;
                float w6  = __builtin_amdgcn_fractf(6.f * cx);
                float s6  = __builtin_amdgcn_sinf(w6);
                float c6  = __builtin_amdgcn_cosf(w6);
                float s12 = 2.f * s6 * c6;
                float c12 = fmaf(2.f * c6, c6, -1.f);
                float s11 = s12 * cx1 - c12 * sx1;
                float sp = hb ? s11 : -sx1;
                float sc = hb ? s12 : 0.f;
                const float* Tr = Tw + mr * TROWSTR + 12 * h;
                float res = 0.f;
#pragma unroll
                for (int w = 0; w < 12; ++w) {
                    res = fmaf(sc, Tr[w], res);
                    float nxr = fmaf(c2x, sc, -sp);
                    sp = sc; sc = nxr;
                }
                res += __shfl_xor(res, 32);
                if (lane < 32 && rep == 0) out[pp0 + mr] = res;
            } else if (V == 1) {
                tokacc += acc[0];                       // keep MFMA chain live
            } else {
                // V==2: scatter+epilogue VALU/LDS phases, using zero acc
                if (mr < 24) {
#pragma unroll
                    for (int r = 0; r < 16; ++r) {
                        int row = (r & 3) + 8 * (r >> 2) + 4 * h;
                        Tw[row * TROWSTR + mr] = acc[r];
                    }
                }
                asm volatile("s_waitcnt lgkmcnt(0)" ::: "memory");
                float sx1 = __builtin_amdgcn_sinf(cx);
                float cx1 = __builtin_amdgcn_cosf(cx);
                const float c2x = 2.f * cx1;
                float sp = -sx1, sc = 0.f, res = 0.f;
                const float* Tr = Tw + mr * TROWSTR + 12 * h;
#pragma unroll
                for (int w = 0; w < 12; ++w) {
                    res = fmaf(sc, Tr[w], res);
                    float nxr = fmaf(c2x, sc, -sp);
                    sp = sc; sc = nxr;
                }
                tokacc += res;
            }

            cx = nx; cy = ny; cz = nz;
        }
    }

    if (V != 0 && lane == 0) tok[blockIdx.x * 4 + wave] = tokacc;  // keep variants live
}

extern "C" void kernel_launch(void* const* d_in, const int* in_sizes, int n_in,
                              void* d_out, int out_size, void* d_ws, size_t ws_size,
                              hipStream_t stream) {
    const float* xyz    = (const float*)d_in[0];
    const float* coeffs = (const float*)d_in[1];
    float* out = (float*)d_out;
    f16x8* wsB = (f16x8*)d_ws;                        // 36864 B
    float* tok = (float*)((char*)d_ws + 65536);       // token sink (ws scratch)

    prep_B<<<9, 256, 0, stream>>>(coeffs, wsB);

    const int n = in_sizes[0] / 3;                    // 524288 = 512 blocks * 4 * 256
    const int grid = n / 1024;
    fourier_probe<0><<<grid, 256, 0, stream>>>(xyz, wsB, out, tok);  // correct output
    fourier_probe<1><<<grid, 256, 0, stream>>>(xyz, wsB, out, tok);  // MFMA-only floor
    fourier_probe<2><<<grid, 256, 0, stream>>>(xyz, wsB, out, tok);  // VALU-only floor
}

// Round 18
// 31.460 us; speedup vs baseline: 3.0247x; 3.0247x over previous
//
#include <hip/hip_runtime.h>

typedef _Float16 f16x2 __attribute__((ext_vector_type(2)));
typedef _Float16 f16x8 __attribute__((ext_vector_type(8)));
typedef __fp16   fp16v2 __attribute__((ext_vector_type(2)));
typedef float    f32x16 __attribute__((ext_vector_type(16)));
typedef unsigned int u32x4 __attribute__((ext_vector_type(4)));

#define TROWSTR 25   // T row stride in words (coprime 32 -> conflict-free epilogue)

__device__ __forceinline__ f16x2 pk2(float lo, float hi) {
    fp16v2 p = __builtin_amdgcn_cvt_pkrtz(lo, hi);
    return __builtin_bit_cast(f16x2, p);
}
__device__ __forceinline__ unsigned int pkbits(f16x2 a, f16x2 b) {
    f16x2 r = a * b;
    return __builtin_bit_cast(unsigned int, r);
}

// ---- prep: C (f32) -> flattened-K f16 B table (validated R10) ----
// wsB[s*64 + l][e] = f16(C[i][kk]), i = l&31 (0 if i>=24), kk = 16s + 8*(l>>5) + e
__global__ __launch_bounds__(256) void prep_B(const float* __restrict__ coeffs,
                                              f16x8* __restrict__ wsB)
{
    int chunk = blockIdx.x * 256 + threadIdx.x;   // 0..2303 = 36 steps * 64 lanes
    int s = chunk >> 6, l = chunk & 63;
    int i = l & 31, h = l >> 5;
    f16x8 v;
    if (i < 24) {
        const float* src = coeffs + i * 576 + 16 * s + 8 * h;
#pragma unroll
        for (int e = 0; e < 8; ++e) v[e] = (_Float16)src[e];
    } else {
#pragma unroll
        for (int e = 0; e < 8; ++e) v[e] = (_Float16)0.f;
    }
    wsB[chunk] = v;
}

// ---- main: LDS-B + phase-diverse occupancy (R17 diagnosis: V0 = V1+V2, zero
// MFMA/VALU overlap from lockstep waves; AGPR-pin shuffles were phantom VALU).
// Block = 512 (8 waves), grid = 512 -> 2 independent blocks/CU, 4 waves/SIMD.
// Each wave: 128 points = 4 iters of one 32x32 M-tile. B staged once to LDS;
// one ds_read_b128 per K-step; NO barriers after staging (T wave-private).
// Flattened K (validated R10): step s (1..35), elem e: kk=16s+8h+e;
// j=(2s+h)/3 (compile-time per half), k=8*((2s+h)%3)+e.
// Native v_sin/v_cos take REVOLUTIONS: sin(2pi*x) = __builtin_amdgcn_sinf(x).
__global__ __launch_bounds__(512) void fourier_main(
    const float* __restrict__ xyz,
    const f16x8* __restrict__ wsB,
    float* __restrict__ out)
{
    __shared__ __align__(16) f16x8 Bl[2304];                   // 36864 B
    __shared__ __align__(16) float Tls[8 * 32 * TROWSTR];      // 25600 B

    const int tid  = threadIdx.x;
    const int wave = tid >> 6;
    const int lane = tid & 63;
    const int h    = lane >> 5;
    const int mr   = lane & 31;
    const bool hb  = (h != 0);

    const int pw = (blockIdx.x * 8 + wave) * 128;   // wave's 128 points

    // ---- stage B once per block (coalesced 16B copies from pre-converted ws) ----
#pragma unroll
    for (int pass = 0; pass < 4; ++pass)
        Bl[pass * 512 + tid] = wsB[pass * 512 + tid];
    if (tid < 256) Bl[2048 + tid] = wsB[2048 + tid];

    float cx = xyz[3 * (pw + mr) + 0];
    float cy = xyz[3 * (pw + mr) + 1];
    float cz = xyz[3 * (pw + mr) + 2];

    float* Tw = Tls + wave * (32 * TROWSTR);

    __syncthreads();   // staging complete; the ONLY barrier in the kernel

#pragma unroll 1
    for (int it = 0; it < 4; ++it) {
        const int pp0 = pw + it * 32;

        // prefetch next iteration's point EARLY (hides HBM under trig+MFMA)
        int pn = (it < 3) ? (pp0 + 32 + mr) : (pw + mr);
        float nx = xyz[3 * pn + 0];
        float ny = xyz[3 * pn + 1];
        float nz = xyz[3 * pn + 2];

        // ---- trig setup (validated R16 math) ----
        float s1y = __builtin_amdgcn_sinf(cy);
        float c1y = __builtin_amdgcn_cosf(cy);
        float c2y = 2.f * c1y;
        float syv[24];
        syv[0] = 0.f; syv[1] = s1y;
#pragma unroll
        for (int j = 2; j < 24; ++j) syv[j] = fmaf(c2y, syv[j - 1], -syv[j - 2]);
        // per-iter f16x2 broadcast table (kills per-step cvt)
        unsigned int hyt[24];
#pragma unroll
        for (int j = 0; j < 24; ++j)
            hyt[j] = __builtin_bit_cast(unsigned int, pk2(syv[j], syv[j]));

        float s1 = __builtin_amdgcn_sinf(cz);
        float c1 = __builtin_amdgcn_cosf(cz);
        float w8 = __builtin_amdgcn_fractf(8.f * cz);
        float s8 = __builtin_amdgcn_sinf(w8);
        float c8 = __builtin_amdgcn_cosf(w8);
        float s16 = 2.f * s8 * c8;
        float c16 = fmaf(2.f * c8, c8, -1.f);
        float c2z = 2.f * c1;

        f16x2 szR[3][4];   // rotated bank t holds k0 = 8*((t+h)%3)  (validated)
#pragma unroll
        for (int t = 0; t < 3; ++t) {
            float sk, ck;
            if (t == 0) { sk = hb ? s8  : 0.f;  ck = hb ? c8  : 1.f;  }
            if (t == 1) { sk = hb ? s16 : s8;   ck = hb ? c16 : c8;   }
            if (t == 2) { sk = hb ? 0.f : s16;  ck = hb ? 1.f : c16;  }
            float v[8];
            v[0] = sk;
            v[1] = fmaf(sk, c1, ck * s1);
#pragma unroll
            for (int e = 2; e < 8; ++e) v[e] = fmaf(c2z, v[e - 1], -v[e - 2]);
#pragma unroll
            for (int q = 0; q < 4; ++q) szR[t][q] = pk2(v[2 * q], v[2 * q + 1]);
        }

        f32x16 acc = {};

        // ---- main loop: 1 ds_read_b128 + A-build (5 VALU) + 1 MFMA per step ----
#pragma unroll
        for (int s = 1; s < 36; ++s) {
            f16x8 bs = Bl[s * 64 + lane];      // imm-offset ds_read_b128
            const int t  = (2 * s) % 3;
            const int j0 = (2 * s) / 3;        // compile-time
            const int j1 = (2 * s + 1) / 3;    // compile-time
            unsigned int hw = (j0 == j1) ? hyt[j0] : (hb ? hyt[j1] : hyt[j0]);
            f16x2 hy2 = __builtin_bit_cast(f16x2, hw);
            u32x4 aw;
            aw[0] = pkbits(hy2, szR[t][0]);
            aw[1] = pkbits(hy2, szR[t][1]);
            aw[2] = pkbits(hy2, szR[t][2]);
            aw[3] = pkbits(hy2, szR[t][3]);
            f16x8 a = __builtin_bit_cast(f16x8, aw);
            acc = __builtin_amdgcn_mfma_f32_32x32x16_f16(a, bs, acc, 0, 0, 0);
        }

        // ---- scatter T[point][i]: point=D row=(r&3)+8*(r>>2)+4h, i=D col=mr ----
        if (mr < 24) {
#pragma unroll
            for (int r = 0; r < 16; ++r) {
                int row = (r & 3) + 8 * (r >> 2) + 4 * h;
                Tw[row * TROWSTR + mr] = acc[r];
            }
        }
        asm volatile("s_waitcnt lgkmcnt(0)" ::: "memory");   // wave-local drain

        // ---- epilogue, h-split over i: h half sums i=12h..12h+11 (validated R15) ----
        {
            float sx1 = __builtin_amdgcn_sinf(cx);
            float cx1 = __builtin_amdgcn_cosf(cx);
            const float c2x = 2.f * cx1;
            float w6  = __builtin_amdgcn_fractf(6.f * cx);
            float s6  = __builtin_amdgcn_sinf(w6);
            float c6  = __builtin_amdgcn_cosf(w6);
            float s12 = 2.f * s6 * c6;
            float c12 = fmaf(2.f * c6, c6, -1.f);
            float s11 = s12 * cx1 - c12 * sx1;
            float sp = hb ? s11 : -sx1;
            float sc = hb ? s12 : 0.f;
            const float* Tr = Tw + mr * TROWSTR + 12 * h;
            float res = 0.f;
#pragma unroll
            for (int w = 0; w < 12; ++w) {
                res = fmaf(sc, Tr[w], res);
                float nxr = fmaf(c2x, sc, -sp);
                sp = sc; sc = nxr;
            }
            res += __shfl_xor(res, 32);
            if (lane < 32) out[pp0 + mr] = res;
        }

        cx = nx; cy = ny; cz = nz;
    }
}

extern "C" void kernel_launch(void* const* d_in, const int* in_sizes, int n_in,
                              void* d_out, int out_size, void* d_ws, size_t ws_size,
                              hipStream_t stream) {
    const float* xyz    = (const float*)d_in[0];
    const float* coeffs = (const float*)d_in[1];
    float* out = (float*)d_out;
    f16x8* wsB = (f16x8*)d_ws;                 // needs 36864 B

    prep_B<<<9, 256, 0, stream>>>(coeffs, wsB);

    const int n = in_sizes[0] / 3;             // 524288 = 512 blocks * 8 waves * 128
    const int grid = n / 1024;
    fourier_main<<<grid, 512, 0, stream>>>(xyz, wsB, out);
}